// Round 1
// baseline (653.666 us; speedup 1.0000x reference)
//
#include <hip/hip_runtime.h>

#define BB 256
#define TT 512
#define CC 128

__device__ __forceinline__ bool mask_at(const void* mask, bool is_u8, int idx) {
    if (is_u8) return ((const unsigned char*)mask)[idx] != 0;
    return ((const int*)mask)[idx] != 0;
}

// Forward algorithm (log partition) in exp-domain. One block per batch,
// 128 threads: thread j owns output column j; E[:,j] held in 128 VGPRs.
__global__ __launch_bounds__(128, 1)
void crf_forward(const float* __restrict__ em_all,
                 const void* __restrict__ mask,
                 const float* __restrict__ transitions,
                 float* __restrict__ log_den)
{
    const int b = blockIdx.x;
    const int j = threadIdx.x;
    const int lane = j & 63;
    const int wid = j >> 6;

    __shared__ float4 aexp4[CC / 4];
    __shared__ float redf[2];
    __shared__ int redi[2];
    float* aexp = (float*)aexp4;

    const unsigned char* mb = (const unsigned char*)mask;
    const bool is_u8 = (mb[1] != 0);  // lengths >= 256 so mask[0][1] is true

    // ---- per-batch length (mask is prefix-true) ----
    int cnt = 0;
    #pragma unroll
    for (int k = 0; k < TT / CC; ++k)
        cnt += mask_at(mask, is_u8, b * TT + j + k * CC) ? 1 : 0;
    #pragma unroll
    for (int off = 32; off; off >>= 1) cnt += __shfl_xor(cnt, off);
    if (lane == 0) redi[wid] = cnt;
    __syncthreads();
    const int len = redi[0] + redi[1];

    // ---- E column j in registers: Ec[i] = exp(T[i][j]) ----
    float Ec[CC];
    #pragma unroll
    for (int i = 0; i < CC; ++i) Ec[i] = __expf(transitions[i * CC + j]);

    const float* em = em_all + (size_t)b * TT * CC;
    float la = em[j];                      // t = 0 init
    float emit_next = (len > 1) ? em[CC + j] : 0.f;

    for (int t = 1; t < len; ++t) {
        const float emit_cur = emit_next;
        float en = 0.f;
        if (t + 1 < len) en = em[(t + 1) * CC + j];  // prefetch next step
        emit_next = en;

        // block max of la (renormalization shift)
        float wm = la;
        #pragma unroll
        for (int off = 32; off; off >>= 1) wm = fmaxf(wm, __shfl_xor(wm, off));
        if (lane == 0) redf[wid] = wm;
        __syncthreads();
        const float m = fmaxf(redf[0], redf[1]);
        aexp[j] = __expf(la - m);
        __syncthreads();

        // matvec: v_j = sum_i aexp[i] * E[i][j]
        float a0 = 0.f, a1 = 0.f, a2 = 0.f, a3 = 0.f;
        #pragma unroll
        for (int i4 = 0; i4 < CC / 4; ++i4) {
            const float4 a4 = aexp4[i4];   // LDS broadcast (same addr all lanes)
            a0 = fmaf(a4.x, Ec[4 * i4 + 0], a0);
            a1 = fmaf(a4.y, Ec[4 * i4 + 1], a1);
            a2 = fmaf(a4.z, Ec[4 * i4 + 2], a2);
            a3 = fmaf(a4.w, Ec[4 * i4 + 3], a3);
        }
        const float v = (a0 + a1) + (a2 + a3);
        la = __logf(v) + m + emit_cur;
    }

    // ---- log_den[b] = logsumexp_j(la_j) ----
    float wm = la;
    #pragma unroll
    for (int off = 32; off; off >>= 1) wm = fmaxf(wm, __shfl_xor(wm, off));
    if (lane == 0) redf[wid] = wm;
    __syncthreads();
    const float m = fmaxf(redf[0], redf[1]);
    float p = __expf(la - m);
    #pragma unroll
    for (int off = 32; off; off >>= 1) p += __shfl_xor(p, off);
    __syncthreads();               // everyone done reading redf for m
    if (lane == 0) redf[wid] = p;
    __syncthreads();
    if (j == 0) log_den[b] = m + __logf(redf[0] + redf[1]);
}

// Gold-path score: sum of masked emissions at tags + masked pair transitions.
__global__ __launch_bounds__(256)
void crf_num(const float* __restrict__ em_all,
             const int* __restrict__ tags,
             const void* __restrict__ mask,
             const float* __restrict__ transitions,
             float* __restrict__ log_num)
{
    const int b = blockIdx.x;
    const int j = threadIdx.x;
    const int lane = j & 63;
    const int wid = j >> 6;
    __shared__ float redf[4];

    const unsigned char* mb = (const unsigned char*)mask;
    const bool is_u8 = (mb[1] != 0);

    const float* em = em_all + (size_t)b * TT * CC;
    const int* tg = tags + b * TT;

    float s = 0.f;
    for (int t = j; t < TT; t += 256) {
        const bool mt = mask_at(mask, is_u8, b * TT + t);
        if (mt) {
            s += em[t * CC + tg[t]];
            if (t >= 1 && mask_at(mask, is_u8, b * TT + t - 1))
                s += transitions[tg[t - 1] * CC + tg[t]];
        }
    }
    #pragma unroll
    for (int off = 32; off; off >>= 1) s += __shfl_xor(s, off);
    if (lane == 0) redf[wid] = s;
    __syncthreads();
    if (j == 0) log_num[b] = redf[0] + redf[1] + redf[2] + redf[3];
}

__global__ __launch_bounds__(256)
void crf_final(const float* __restrict__ log_den,
               const float* __restrict__ log_num,
               float* __restrict__ out)
{
    const int j = threadIdx.x;   // one thread per batch, B == 256
    const int lane = j & 63;
    const int wid = j >> 6;
    __shared__ float redf[4];
    float v = log_den[j] - log_num[j];
    #pragma unroll
    for (int off = 32; off; off >>= 1) v += __shfl_xor(v, off);
    if (lane == 0) redf[wid] = v;
    __syncthreads();
    if (j == 0) out[0] = (redf[0] + redf[1] + redf[2] + redf[3]) * (1.0f / BB);
}

extern "C" void kernel_launch(void* const* d_in, const int* in_sizes, int n_in,
                              void* d_out, int out_size, void* d_ws, size_t ws_size,
                              hipStream_t stream) {
    const float* emissions   = (const float*)d_in[0];
    const int*   tags        = (const int*)d_in[1];
    const void*  mask        = d_in[2];
    const float* transitions = (const float*)d_in[3];
    float* out = (float*)d_out;

    float* log_den = (float*)d_ws;
    float* log_num = log_den + BB;

    crf_forward<<<BB, 128, 0, stream>>>(emissions, mask, transitions, log_den);
    crf_num<<<BB, 256, 0, stream>>>(emissions, tags, mask, transitions, log_num);
    crf_final<<<1, 256, 0, stream>>>(log_den, log_num, out);
}